// Round 6
// baseline (407.144 us; speedup 1.0000x reference)
//
#include <hip/hip_runtime.h>
#include <hip/hip_bf16.h>
#include <math.h>

// ---------------------------------------------------------------------------
// Round 6: long-burst transpose (256k x 32n tiles, bf16-split before LDS,
//   512 B contiguous stores per output row), reduce_prod fused into mlp2.
//   gemm128 / pq_gemm / build_y1 / reduce4 / reduce8 unchanged from round 5.
// ---------------------------------------------------------------------------

typedef __attribute__((ext_vector_type(8))) short short8;
typedef __attribute__((ext_vector_type(4))) float floatx4;

#define AS1 __attribute__((address_space(1)))
#define AS3 __attribute__((address_space(3)))
#define GLD16(g, l) __builtin_amdgcn_global_load_lds((AS1 const unsigned int*)(g), (AS3 unsigned int*)(l), 16, 0, 0)

__device__ __forceinline__ float silu_f(float x) {
    return x / (1.0f + __expf(-x));
}

// RNE split of fp32 into two bf16 (hi + lo)
__device__ __forceinline__ void split2(float x, unsigned short& hi, unsigned short& lo) {
    unsigned u = __float_as_uint(x);
    unsigned r = u + 0x7FFFu + ((u >> 16) & 1u);
    unsigned short h = (unsigned short)(r >> 16);
    float hf = __uint_as_float((unsigned)h << 16);
    float rem = x - hf;
    unsigned u2 = __float_as_uint(rem);
    unsigned r2 = u2 + 0x7FFFu + ((u2 >> 16) & 1u);
    hi = h;
    lo = (unsigned short)(r2 >> 16);
}

// ---------------- transpose + split, 256k x 32n tiles ----------------------
// W[K][N] f32 -> Th[N][K], Tl[N][K] bf16 (k-contiguous).
// Phase 1: thread t = k-offset: load 32 fp32 (128 B contiguous) of row k0+t,
//   split -> write u16 columns into LDS planes hi/lo [32 n][264 pitch].
// Phase 2: thread (n = t>>3, ks = (t&3 bits)*32): read 4 b128 per plane,
//   store 64 B contiguous per plane; 8 threads cover 512 B of one n-row.
#define TPITCH 264
__global__ __launch_bounds__(256)
void transpose_split_all(const float* __restrict__ w10, const float* __restrict__ w11,
                         const float* __restrict__ w12, const float* __restrict__ h_one,
                         unsigned short* __restrict__ t10h, unsigned short* __restrict__ t10l,
                         unsigned short* __restrict__ t11h, unsigned short* __restrict__ t11l,
                         unsigned short* __restrict__ t12h, unsigned short* __restrict__ t12l,
                         unsigned short* __restrict__ Hh, unsigned short* __restrict__ Hl) {
    const int t = threadIdx.x;
    int id = blockIdx.x;

    if (id >= 4096) {
        // split_h tail: 8 blocks x 4096 elements (h_one = 32x1024)
        const int base = (id - 4096) * 4096 + t * 16;
        #pragma unroll
        for (int j = 0; j < 4; ++j) {
            float4 v = *(const float4*)&h_one[base + 4 * j];
            ushort4 hv, lv;
            split2(v.x, hv.x, lv.x);
            split2(v.y, hv.y, lv.y);
            split2(v.z, hv.z, lv.z);
            split2(v.w, hv.w, lv.w);
            *(ushort4*)&Hh[base + 4 * j] = hv;
            *(ushort4*)&Hl[base + 4 * j] = lv;
        }
        return;
    }

    const float* W;
    unsigned short *Th, *Tl;
    int K, N, nt, kt;
    // tiles: w10 8k x 128n = 1024; w11 16 x 128 = 2048; w12 16 x 64 = 1024
    if (id < 1024)       { W = w10; Th = t10h; Tl = t10l; K = 2048; N = 4096; nt = id & 127; kt = id >> 7; }
    else if (id < 3072)  { id -= 1024; W = w11; Th = t11h; Tl = t11l; K = 4096; N = 4096; nt = id & 127; kt = id >> 7; }
    else                 { id -= 3072; W = w12; Th = t12h; Tl = t12l; K = 4096; N = 2048; nt = id & 63;  kt = id >> 6; }

    __shared__ unsigned short hs_t[32][TPITCH];
    __shared__ unsigned short ls_t[32][TPITCH];
    const int n0 = nt * 32;
    const int k0 = kt * 256;

    // phase 1: row k0+t, 32 contiguous n
    const float* src = &W[(size_t)(k0 + t) * N + n0];
    #pragma unroll
    for (int j = 0; j < 8; ++j) {
        float4 v = *(const float4*)(src + 4 * j);
        unsigned short h0, l0, h1, l1, h2, l2, h3, l3;
        split2(v.x, h0, l0);
        split2(v.y, h1, l1);
        split2(v.z, h2, l2);
        split2(v.w, h3, l3);
        hs_t[4 * j + 0][t] = h0; ls_t[4 * j + 0][t] = l0;
        hs_t[4 * j + 1][t] = h1; ls_t[4 * j + 1][t] = l1;
        hs_t[4 * j + 2][t] = h2; ls_t[4 * j + 2][t] = l2;
        hs_t[4 * j + 3][t] = h3; ls_t[4 * j + 3][t] = l3;
    }
    __syncthreads();

    // phase 2: output row n0+sn, k segment [k0+ks, +32)
    const int sn = t >> 3;
    const int ks = (t & 7) * 32;
    unsigned short* dh = &Th[(size_t)(n0 + sn) * K + k0 + ks];
    unsigned short* dl = &Tl[(size_t)(n0 + sn) * K + k0 + ks];
    #pragma unroll
    for (int c = 0; c < 4; ++c)
        *(short8*)(dh + 8 * c) = *(const short8*)&hs_t[sn][ks + 8 * c];
    #pragma unroll
    for (int c = 0; c < 4; ++c)
        *(short8*)(dl + 8 * c) = *(const short8*)&ls_t[sn][ks + 8 * c];
}

// ---------------- m97-style LDS-staged GEMM, 128x128 tile ------------------
__global__ __launch_bounds__(256, 2)
void gemm128(const unsigned short* __restrict__ Ah, const unsigned short* __restrict__ Al,
             const unsigned short* __restrict__ Bh, const unsigned short* __restrict__ Bl,
             int K, float* __restrict__ Cpart, int N, int Mtot, int kc)
{
    __shared__ __align__(16) unsigned short As[2][128][32];
    __shared__ __align__(16) unsigned short Bs[2][128][32];

    const int tid  = threadIdx.x;
    const int lane = tid & 63;
    const int wid  = tid >> 6;
    const int n0 = blockIdx.x * 128;
    const int m0 = blockIdx.y * 128;
    const int kbase = blockIdx.z * kc;

    const int srow   = wid * 32 + (lane >> 2);
    const int schunk = (lane & 3) ^ ((srow >> 1) & 3);
    const unsigned short* gA0h = Ah + (size_t)(m0 + srow) * K + kbase + schunk * 8;
    const unsigned short* gA1h = gA0h + (size_t)16 * K;
    const unsigned short* gA0l = Al + (size_t)(m0 + srow) * K + kbase + schunk * 8;
    const unsigned short* gA1l = gA0l + (size_t)16 * K;
    const unsigned short* gB0h = Bh + (size_t)(n0 + srow) * K + kbase + schunk * 8;
    const unsigned short* gB1h = gB0h + (size_t)16 * K;
    const unsigned short* gB0l = Bl + (size_t)(n0 + srow) * K + kbase + schunk * 8;
    const unsigned short* gB1l = gB0l + (size_t)16 * K;
    unsigned short* lA0h = &As[0][wid * 32][0];
    unsigned short* lA1h = &As[0][wid * 32 + 16][0];
    unsigned short* lA0l = &As[1][wid * 32][0];
    unsigned short* lA1l = &As[1][wid * 32 + 16][0];
    unsigned short* lB0h = &Bs[0][wid * 32][0];
    unsigned short* lB1h = &Bs[0][wid * 32 + 16][0];
    unsigned short* lB0l = &Bs[1][wid * 32][0];
    unsigned short* lB1l = &Bs[1][wid * 32 + 16][0];

    const int mhalf = wid >> 1;
    const int nhalf = wid & 1;
    const int lm = lane & 15;
    const int q  = lane >> 4;
    int aoffs[4], boffs[4];
    #pragma unroll
    for (int f = 0; f < 4; ++f) {
        int arow = mhalf * 64 + f * 16 + lm;
        int aslot = q ^ ((arow >> 1) & 3);
        aoffs[f] = arow * 32 + aslot * 8;
        int brow = nhalf * 64 + f * 16 + lm;
        int bslot = q ^ ((brow >> 1) & 3);
        boffs[f] = brow * 32 + bslot * 8;
    }
    const unsigned short* AsF = &As[0][0][0];
    const unsigned short* BsF = &Bs[0][0][0];

    floatx4 acc[4][4];
    #pragma unroll
    for (int ms = 0; ms < 4; ++ms)
        #pragma unroll
        for (int ns = 0; ns < 4; ++ns)
            acc[ms][ns] = (floatx4){0.f, 0.f, 0.f, 0.f};

    const int S = kc >> 5;
    for (int s = 0; s < S; ++s) {
        const int ko = s << 5;
        __syncthreads();
        GLD16(gA0h + ko, lA0h);
        GLD16(gA1h + ko, lA1h);
        GLD16(gA0l + ko, lA0l);
        GLD16(gA1l + ko, lA1l);
        GLD16(gB0h + ko, lB0h);
        GLD16(gB1h + ko, lB1h);
        GLD16(gB0l + ko, lB0l);
        GLD16(gB1l + ko, lB1l);
        __syncthreads();

        short8 afh[4], afl[4], bfh[4], bfl[4];
        #pragma unroll
        for (int f = 0; f < 4; ++f) {
            afh[f] = *(const short8*)(AsF + aoffs[f]);
            afl[f] = *(const short8*)(AsF + 4096 + aoffs[f]);
            bfh[f] = *(const short8*)(BsF + boffs[f]);
            bfl[f] = *(const short8*)(BsF + 4096 + boffs[f]);
        }
        #pragma unroll
        for (int ms = 0; ms < 4; ++ms)
            #pragma unroll
            for (int ns = 0; ns < 4; ++ns)
                acc[ms][ns] = __builtin_amdgcn_mfma_f32_16x16x32_bf16(afh[ms], bfh[ns], acc[ms][ns], 0, 0, 0);
        #pragma unroll
        for (int ms = 0; ms < 4; ++ms)
            #pragma unroll
            for (int ns = 0; ns < 4; ++ns)
                acc[ms][ns] = __builtin_amdgcn_mfma_f32_16x16x32_bf16(afl[ms], bfh[ns], acc[ms][ns], 0, 0, 0);
        #pragma unroll
        for (int ms = 0; ms < 4; ++ms)
            #pragma unroll
            for (int ns = 0; ns < 4; ++ns)
                acc[ms][ns] = __builtin_amdgcn_mfma_f32_16x16x32_bf16(afh[ms], bfl[ns], acc[ms][ns], 0, 0, 0);
    }

    float* Cp = Cpart + (size_t)blockIdx.z * Mtot * N;
    const int lr = (lane >> 4) * 4;
    #pragma unroll
    for (int ms = 0; ms < 4; ++ms)
        #pragma unroll
        for (int ns = 0; ns < 4; ++ns)
            #pragma unroll
            for (int r = 0; r < 4; ++r)
                Cp[(size_t)(m0 + mhalf * 64 + ms * 16 + lr + r) * N + n0 + nhalf * 64 + ns * 16 + lm] = acc[ms][ns][r];
}

// ---------------- P/Q GEMM (LDS-free) --------------------------------------
__device__ __forceinline__ void load_set(
    const unsigned short* __restrict__ Ah, const unsigned short* __restrict__ Al,
    const unsigned short* __restrict__ Bh, const unsigned short* __restrict__ Bl,
    const unsigned aoff[4], const unsigned boff[4], int koff,
    short8 (&ah)[4], short8 (&al)[4], short8 (&bh)[4], short8 (&bl)[4])
{
    #pragma unroll
    for (int i = 0; i < 4; ++i) {
        ah[i] = *(const short8*)(Ah + aoff[i] + koff);
        al[i] = *(const short8*)(Al + aoff[i] + koff);
        bh[i] = *(const short8*)(Bh + boff[i] + koff);
        bl[i] = *(const short8*)(Bl + boff[i] + koff);
    }
}

__device__ __forceinline__ void mfma_set(
    const short8 (&ah)[4], const short8 (&al)[4],
    const short8 (&bh)[4], const short8 (&bl)[4],
    floatx4 (&acc)[4][4])
{
    #pragma unroll
    for (int ms = 0; ms < 4; ++ms)
        #pragma unroll
        for (int ns = 0; ns < 4; ++ns)
            acc[ms][ns] = __builtin_amdgcn_mfma_f32_16x16x32_bf16(ah[ms], bh[ns], acc[ms][ns], 0, 0, 0);
    #pragma unroll
    for (int ms = 0; ms < 4; ++ms)
        #pragma unroll
        for (int ns = 0; ns < 4; ++ns)
            acc[ms][ns] = __builtin_amdgcn_mfma_f32_16x16x32_bf16(al[ms], bh[ns], acc[ms][ns], 0, 0, 0);
    #pragma unroll
    for (int ms = 0; ms < 4; ++ms)
        #pragma unroll
        for (int ns = 0; ns < 4; ++ns)
            acc[ms][ns] = __builtin_amdgcn_mfma_f32_16x16x32_bf16(ah[ms], bl[ns], acc[ms][ns], 0, 0, 0);
}

__global__ __launch_bounds__(256, 2)
void pq_gemm(const unsigned short* __restrict__ Ah, const unsigned short* __restrict__ Al,
             const unsigned short* __restrict__ Bh0, const unsigned short* __restrict__ Bl0,
             float* __restrict__ PQ)
{
    const int tid  = threadIdx.x;
    const int lane = tid & 63;
    const int wid  = tid >> 6;
    const int n0 = blockIdx.x * 256 + wid * 64;
    const int z  = blockIdx.z;
    const int kbase = (z & 1) * 512;
    const unsigned short* Bh = Bh0 + (z >> 1) * 1024;
    const unsigned short* Bl = Bl0 + (z >> 1) * 1024;
    const int lm = lane & 15;
    const int lk = (lane >> 4) * 8;

    unsigned aoff[4], boff[4];
    #pragma unroll
    for (int i = 0; i < 4; ++i) {
        aoff[i] = (unsigned)(i * 16 + lm) * 1024 + kbase + lk;
        boff[i] = (unsigned)(n0 + i * 16 + lm) * 2048 + kbase + lk;
    }

    floatx4 acc[4][4];
    #pragma unroll
    for (int ms = 0; ms < 4; ++ms)
        #pragma unroll
        for (int ns = 0; ns < 4; ++ns)
            acc[ms][ns] = (floatx4){0.f, 0.f, 0.f, 0.f};

    short8 a0h[4], a0l[4], b0h[4], b0l[4];
    short8 a1h[4], a1l[4], b1h[4], b1l[4];

    load_set(Ah, Al, Bh, Bl, aoff, boff, 0, a0h, a0l, b0h, b0l);
    for (int s = 0; s + 1 < 16; s += 2) {
        load_set(Ah, Al, Bh, Bl, aoff, boff, (s + 1) << 5, a1h, a1l, b1h, b1l);
        mfma_set(a0h, a0l, b0h, b0l, acc);
        if (s + 2 < 16)
            load_set(Ah, Al, Bh, Bl, aoff, boff, (s + 2) << 5, a0h, a0l, b0h, b0l);
        mfma_set(a1h, a1l, b1h, b1l, acc);
    }

    float* Cp = PQ + (size_t)z * 64 * 4096;
    const int lr = (lane >> 4) * 4;
    #pragma unroll
    for (int ms = 0; ms < 4; ++ms)
        #pragma unroll
        for (int ns = 0; ns < 4; ++ns)
            #pragma unroll
            for (int r = 0; r < 4; ++r)
                Cp[(size_t)(ms * 16 + lr + r) * 4096 + n0 + ns * 16 + lm] = acc[ms][ns][r];
}

// ---------------- small kernels ----------------
__global__ __launch_bounds__(256)
void build_y1_kernel(const float* __restrict__ PQ, const float* __restrict__ b1,
                     unsigned short* __restrict__ Y1h, unsigned short* __restrict__ Y1l) {
    const int r = blockIdx.x;
    const int g = r / 240;
    const int rem = r % 240;
    const int o = rem / 120;
    const int p = rem % 120;
    int i = 0, pp = p, cnt = 15;
    while (pp >= cnt) { pp -= cnt; cnt--; i++; }
    const int j = i + 1 + pp;
    const int ai = g * 16 + (o ? j : i);
    const int bi = g * 16 + (o ? i : j);
    const size_t chunk4 = (size_t)64 * 4096 / 4;
    const float4* Pr0 = (const float4*)(PQ + (size_t)ai * 4096);
    const float4* Qr0 = (const float4*)(PQ + (size_t)2 * 64 * 4096 + (size_t)bi * 4096);
    const float4* Br  = (const float4*)b1;
    for (int c = threadIdx.x; c < 1024; c += 256) {
        float4 p0 = Pr0[c], p1 = Pr0[c + chunk4];
        float4 q0 = Qr0[c], q1 = Qr0[c + chunk4];
        float4 bv = Br[c];
        float s0 = silu_f(p0.x + p1.x + q0.x + q1.x + bv.x);
        float s1 = silu_f(p0.y + p1.y + q0.y + q1.y + bv.y);
        float s2 = silu_f(p0.z + p1.z + q0.z + q1.z + bv.z);
        float s3 = silu_f(p0.w + p1.w + q0.w + q1.w + bv.w);
        ushort4 hv, lv;
        split2(s0, hv.x, lv.x);
        split2(s1, hv.y, lv.y);
        split2(s2, hv.z, lv.z);
        split2(s3, hv.w, lv.w);
        *(ushort4*)&Y1h[(size_t)r * 4096 + c * 4] = hv;
        *(ushort4*)&Y1l[(size_t)r * 4096 + c * 4] = lv;
    }
}

__global__ __launch_bounds__(256)
void reduce4_silu_split(const float* __restrict__ Part, const float* __restrict__ bias,
                        unsigned short* __restrict__ Yh, unsigned short* __restrict__ Yl) {
    const size_t idx = (size_t)blockIdx.x * 256 + threadIdx.x;
    const size_t stride4 = (size_t)512 * 4096 / 4;
    const float4* p = (const float4*)Part;
    float4 v0 = p[idx], v1 = p[idx + stride4], v2 = p[idx + 2 * stride4], v3 = p[idx + 3 * stride4];
    const int col = (int)((idx * 4) & 4095);
    float4 b = *(const float4*)&bias[col];
    float s0 = silu_f(v0.x + v1.x + v2.x + v3.x + b.x);
    float s1 = silu_f(v0.y + v1.y + v2.y + v3.y + b.y);
    float s2 = silu_f(v0.z + v1.z + v2.z + v3.z + b.z);
    float s3 = silu_f(v0.w + v1.w + v2.w + v3.w + b.w);
    ushort4 hv, lv;
    split2(s0, hv.x, lv.x);
    split2(s1, hv.y, lv.y);
    split2(s2, hv.z, lv.z);
    split2(s3, hv.w, lv.w);
    *(ushort4*)&Yh[idx * 4] = hv;
    *(ushort4*)&Yl[idx * 4] = lv;
}

__global__ __launch_bounds__(256)
void reduce8_bias(const float* __restrict__ Part, const float* __restrict__ bias,
                  float* __restrict__ Hb) {
    const size_t idx = (size_t)blockIdx.x * 256 + threadIdx.x;
    const size_t stride4 = (size_t)512 * 2048 / 4;
    const float4* p = (const float4*)Part;
    float4 s = p[idx];
    #pragma unroll
    for (int c = 1; c < 8; ++c) {
        float4 v = p[idx + c * stride4];
        s.x += v.x; s.y += v.y; s.z += v.z; s.w += v.w;
    }
    const int col = (int)((idx * 4) & 2047);
    float4 b = *(const float4*)&bias[col];
    s.x += b.x; s.y += b.y; s.z += b.z; s.w += b.w;
    *(float4*)&Hb[idx * 4] = s;
}

// fused: recompute a-chunk (pair products) then partial mlp2 MACs.
// grid (nc=8, kc=8); Part2[kc][g][n]
__global__ __launch_bounds__(256)
void mlp2_fused_kernel(const float* __restrict__ Hb, const float* __restrict__ W,
                       float* __restrict__ Part2) {
    __shared__ float a0s[256], a1s[256];
    const int kc = blockIdx.y, nc = blockIdx.x, t = threadIdx.x;
    const int c = kc * 256 + t;
    // a[g][c] = prod_p (Hb[g*240+p][c] - Hb[g*240+120+p][c])
    {
        const float* base0 = Hb + c;
        const float* base1 = Hb + (size_t)240 * 2048 + c;
        float pr0 = 1.0f, pr1 = 1.0f;
        #pragma unroll 4
        for (int p = 0; p < 120; ++p) {
            float f0 = base0[(size_t)p * 2048] - base0[(size_t)(120 + p) * 2048];
            float f1 = base1[(size_t)p * 2048] - base1[(size_t)(120 + p) * 2048];
            pr0 *= f0;
            pr1 *= f1;
        }
        a0s[t] = pr0;
        a1s[t] = pr1;
    }
    __syncthreads();
    const int n = nc * 256 + t;
    const float* Wp = W + (size_t)(kc * 256) * 2048 + n;
    float s0 = 0.f, s1 = 0.f;
    #pragma unroll 8
    for (int kk = 0; kk < 256; ++kk) {
        float w = Wp[(size_t)kk * 2048];
        s0 = fmaf(a0s[kk], w, s0);
        s1 = fmaf(a1s[kk], w, s1);
    }
    Part2[kc * 4096 + n] = s0;
    Part2[kc * 4096 + 2048 + n] = s1;
}

__global__ __launch_bounds__(256)
void finalize_kernel(const float* __restrict__ Part2, const float* __restrict__ b2_0,
                     const float* __restrict__ w2_1, const float* __restrict__ b2_1,
                     float* __restrict__ out) {
    __shared__ float red[256];
    const int tid = threadIdx.x;
    float result = 0.0f;
    for (int g = 0; g < 2; ++g) {
        float s = 0.f;
        for (int n = tid; n < 2048; n += 256) {
            float acc = b2_0[n];
            #pragma unroll
            for (int kc = 0; kc < 8; ++kc)
                acc += Part2[kc * 4096 + g * 2048 + n];
            s += tanhf(acc) * w2_1[n];
        }
        red[tid] = s;
        __syncthreads();
        for (int off = 128; off > 0; off >>= 1) {
            if (tid < off) red[tid] += red[tid + off];
            __syncthreads();
        }
        if (tid == 0) result += logf(fabsf(red[0] + b2_1[0]));
        __syncthreads();
    }
    if (tid == 0) out[0] = result;
}

extern "C" void kernel_launch(void* const* d_in, const int* in_sizes, int n_in,
                              void* d_out, int out_size, void* d_ws, size_t ws_size,
                              hipStream_t stream) {
    const float* h_one = (const float*)d_in[0];
    const float* w1_0  = (const float*)d_in[1];
    const float* b1_0  = (const float*)d_in[2];
    const float* w1_1  = (const float*)d_in[3];
    const float* b1_1  = (const float*)d_in[4];
    const float* w1_2  = (const float*)d_in[5];
    const float* b1_2  = (const float*)d_in[6];
    const float* w2_0  = (const float*)d_in[7];
    const float* b2_0  = (const float*)d_in[8];
    const float* w2_1  = (const float*)d_in[9];
    const float* b2_1  = (const float*)d_in[10];
    float* out = (float*)d_out;

    char* ws = (char*)d_ws;
    // region0: W10t (33.5 MB), later PartL1 (4 x 512 x 4096 f32)
    unsigned short* W10t_h = (unsigned short*)ws;
    unsigned short* W10t_l = W10t_h + (size_t)4096 * 2048;
    float*          PartL1 = (float*)ws;
    ws += (size_t)4096 * 2048 * 2 * 2;
    // region1: W11t (67 MB), later PartL2 (8 x 512 x 2048 f32)
    unsigned short* W11t_h = (unsigned short*)ws;
    unsigned short* W11t_l = W11t_h + (size_t)4096 * 4096;
    float*          PartL2 = (float*)ws;
    ws += (size_t)4096 * 4096 * 2 * 2;
    // region2: W12t (33.5 MB), live through L2
    unsigned short* W12t_h = (unsigned short*)ws;
    unsigned short* W12t_l = W12t_h + (size_t)2048 * 4096;
    ws += (size_t)2048 * 4096 * 2 * 2;
    unsigned short* Hh  = (unsigned short*)ws;  ws += (size_t)64 * 1024 * 2;
    unsigned short* Hl  = (unsigned short*)ws;  ws += (size_t)64 * 1024 * 2;
    float* PQ  = (float*)ws;                    ws += (size_t)4 * 64 * 4096 * 4;
    unsigned short* Y1h = (unsigned short*)ws;  ws += (size_t)512 * 4096 * 2;
    unsigned short* Y1l = (unsigned short*)ws;  ws += (size_t)512 * 4096 * 2;
    unsigned short* Y2h = (unsigned short*)ws;  ws += (size_t)512 * 4096 * 2;
    unsigned short* Y2l = (unsigned short*)ws;  ws += (size_t)512 * 4096 * 2;
    float* Hb    = (float*)ws;                  ws += (size_t)512 * 2048 * 4;
    float* Part2 = (float*)ws;                  ws += (size_t)8 * 2 * 2048 * 4;

    // weight transposes + h split (4096 + 8 blocks)
    transpose_split_all<<<4104, 256, 0, stream>>>(w1_0, w1_1, w1_2, h_one,
                                                  W10t_h, W10t_l, W11t_h, W11t_l,
                                                  W12t_h, W12t_l, Hh, Hl);

    // P/Q: one launch, 4 z-slices
    pq_gemm<<<dim3(16, 1, 4), 256, 0, stream>>>(Hh, Hl, W10t_h, W10t_l, PQ);
    build_y1_kernel<<<480, 256, 0, stream>>>(PQ, b1_0, Y1h, Y1l);

    // L1: Y2 = silu(Y1 @ W1_1 + b1_1)  M=512 N=4096 K=4096, Z=4
    gemm128<<<dim3(32, 4, 4), 256, 0, stream>>>(Y1h, Y1l, W11t_h, W11t_l, 4096,
                                                PartL1, 4096, 512, 1024);
    reduce4_silu_split<<<2048, 256, 0, stream>>>(PartL1, b1_1, Y2h, Y2l);

    // L2: Hb = Y2 @ W1_2 + b1_2  M=512 N=2048 K=4096, Z=8
    gemm128<<<dim3(16, 4, 8), 256, 0, stream>>>(Y2h, Y2l, W12t_h, W12t_l, 4096,
                                                PartL2, 2048, 512, 512);
    reduce8_bias<<<1024, 256, 0, stream>>>(PartL2, b1_2, Hb);

    // tail: fused prod + mlp2, then finalize
    mlp2_fused_kernel<<<dim3(8, 8), 256, 0, stream>>>(Hb, w2_0, Part2);
    finalize_kernel<<<1, 256, 0, stream>>>(Part2, b2_0, w2_1, b2_1, out);
}